// Round 6
// baseline (2635.040 us; speedup 1.0000x reference)
//
#include <hip/hip_runtime.h>
#include <hip/hip_bf16.h>

// LSTM: B=64, T=512, V=32000, E=256, H=512, O=1
// Persistent kernel. 4 sync domains (batch groups of 16 sequences), now only
// 8 blocks per domain (512 threads / 8 waves each).  Cross-block h exchange
// via TAGGED 8-byte atomics (tag travels with data: no flags/fences/RMW).
// x(t) gather is pipelined 2 steps ahead through registers + 3-deep LDS
// buffer so emb latency/jitter never touches the h critical path.
#define TB 512
#define NB 64
#define EE 256
#define HH 512
#define NG 4          // batch groups (sync domains)
#define GB 16         // batches per group
#define NBLK 8        // blocks per group
#define NT 512        // threads per block (8 waves)
#define BCOL 256      // gate-cols per block
#define NUNIT 64      // hidden units per block
#define NPB 32        // h pairs per block per batch
#define NPAIR 256     // h pairs per batch (total)
#define NCOLP 260     // P_lds padded row (floats)
#define XD 3          // x_lds pipeline depth

typedef __bf16 bf16_t;
typedef bf16_t bf16x8 __attribute__((ext_vector_type(8)));
typedef float  f32x4  __attribute__((ext_vector_type(4)));
typedef unsigned long long u64;
typedef unsigned u32;

__device__ __forceinline__ float sigf(float x) { return 1.0f / (1.0f + __expf(-x)); }
__device__ __forceinline__ float tanhfast(float x) {
    float xc = fminf(fmaxf(x, -15.0f), 15.0f);
    float e  = __expf(2.0f * xc);
    return (e - 1.0f) / (e + 1.0f);
}
__device__ __forceinline__ unsigned bfbits(float f) {
    bf16_t h = (bf16_t)f;
    return (unsigned)__builtin_bit_cast(unsigned short, h);
}
__device__ __forceinline__ bf16x8 cvt8(float4 a, float4 b) {
    bf16x8 v;
    v[0]=(bf16_t)a.x; v[1]=(bf16_t)a.y; v[2]=(bf16_t)a.z; v[3]=(bf16_t)a.w;
    v[4]=(bf16_t)b.x; v[5]=(bf16_t)b.y; v[6]=(bf16_t)b.z; v[7]=(bf16_t)b.w;
    return v;
}

__global__ __launch_bounds__(NT, 1)
void lstm_persistent(const int* __restrict__ words,
                     const float* __restrict__ emb,
                     const float* __restrict__ Wi,
                     const float* __restrict__ bi,
                     const float* __restrict__ Wh,
                     const float* __restrict__ bh,
                     const float* __restrict__ Wfc,
                     const float* __restrict__ bfc,
                     float* __restrict__ out,        // [64] head + [64*512] h (fp32)
                     u64* __restrict__ tagH)         // [2][NB][NPAIR] tagged pairs
{
    const int tid  = threadIdx.x;
    const int lane = tid & 63;
    const int wv   = tid >> 6;        // 0..7
    const int bg   = blockIdx.x & 3;  // batch group / sync domain
    const int ug   = blockIdx.x >> 2; // unit group 0..7
    const int kgrp = lane >> 4;       // k-octet selector 0..3
    const int cl   = lane & 15;       // A row / B col within 16x16 tile

    __shared__ __align__(16) bf16_t h_lds[16][HH];        // 16 KiB
    __shared__ __align__(16) bf16_t x_lds[XD][16][EE];    // 24 KiB (3-deep)
    __shared__ __align__(16) float  P_lds[16][NCOLP];     // 16.25 KiB

    // zero h_lds (h_{-1} = 0)
    for (int i = tid; i < 16*HH/2; i += NT) ((unsigned*)h_lds)[i] = 0u;

    // ---- weight fragments, stationary in registers for all 512 steps ----
    // local col = u_local*4 + gate ; weight row = gate*H + ug*64 + u_local
    bf16x8 whf[16][2];
    bf16x8 wif[8][2];
    float  biasn[2];
    #pragma unroll
    for (int nt = 0; nt < 2; ++nt) {
        int col = wv*32 + nt*16 + cl;         // 0..255 (local gate-col)
        int ul  = col >> 2, g = col & 3;
        int row = g*HH + ug*NUNIT + ul;
        const float* wr = Wh + (size_t)row*HH;
        #pragma unroll
        for (int kt = 0; kt < 16; ++kt) {
            const float4* p = (const float4*)(wr + kt*32 + kgrp*8);
            whf[kt][nt] = cvt8(p[0], p[1]);
        }
        const float* wir = Wi + (size_t)row*EE;
        #pragma unroll
        for (int kt = 0; kt < 8; ++kt) {
            const float4* p = (const float4*)(wir + kt*32 + kgrp*8);
            wif[kt][nt] = cvt8(p[0], p[1]);
        }
        biasn[nt] = bi[row] + bh[row];
    }

    // x staging coords: row sxb (0..15), chunk sxc (0..31, 8 elems each)
    const int sxb = tid & 15, sxc = tid >> 4;
    const int swzx = (sxb & 7) << 3;
    // h poll/staging coords: batch sbp (0..15), chunk ch (0..31, 8 pairs each)
    const int sbp = tid >> 5, ch = tid & 31;
    const int swzp = (sbp & 7) << 3;

    // prologue: stage x(0) directly; issue x(1) loads into held registers
    {
        int wd = words[(bg*GB + sxb)*TB + 0];
        const float4* p = (const float4*)(emb + (size_t)wd*EE + sxc*8);
        *(bf16x8*)&x_lds[0][sxb][(sxc*8) ^ swzx] = cvt8(p[0], p[1]);
    }
    float4 xf0, xf1;   // held across step boundary: contain x(t+1) during step t
    {
        int wd = words[(bg*GB + sxb)*TB + 1];
        const float4* p = (const float4*)(emb + (size_t)wd*EE + sxc*8);
        xf0 = p[0]; xf1 = p[1];
    }

    float c0 = 0.f, c1 = 0.f;
    __syncthreads();

    for (int t = 0; t < TB; ++t) {
        // ---- input-projection MFMAs from x_lds[t%3] (independent of h) ----
        f32x4 acc0 = { biasn[0], biasn[0], biasn[0], biasn[0] };
        f32x4 acc1 = { biasn[1], biasn[1], biasn[1], biasn[1] };
        const bf16_t (*xl)[EE] = x_lds[t % XD];
        #pragma unroll
        for (int kt = 0; kt < 8; ++kt) {
            bf16x8 a = *(const bf16x8*)&xl[cl][(kt*32 + kgrp*8) ^ ((cl & 7) << 3)];
            acc0 = __builtin_amdgcn_mfma_f32_16x16x32_bf16(a, wif[kt][0], acc0, 0, 0, 0);
            acc1 = __builtin_amdgcn_mfma_f32_16x16x32_bf16(a, wif[kt][1], acc1, 0, 0, 0);
        }

        // ---- stash x(t+1) (regs loaded at step t-1: a full step of slack) ----
        if (t + 1 < TB)
            *(bf16x8*)&x_lds[(t + 1) % XD][sxb][(sxc*8) ^ swzx] = cvt8(xf0, xf1);

        // ---- issue loads for x(t+2); consumed at step t+1's stash ----
        if (t + 2 < TB) {
            int wd = words[(bg*GB + sxb)*TB + (t + 2)];
            const float4* p = (const float4*)(emb + (size_t)wd*EE + sxc*8);
            xf0 = p[0]; xf1 = p[1];
        }

        // ---- poll tagged h_{t-1}: thread owns 8 pairs of one producer ----
        if (t > 0) {
            const u64* src = tagH + ((size_t)((t & 1) ^ 1))*NB*NPAIR
                                  + (size_t)(bg*GB + sbp)*NPAIR + ch*8;
            const u32 tag = (u32)t;
            u64 hv[8];
            for (;;) {
                #pragma unroll
                for (int j = 0; j < 8; ++j)
                    hv[j] = __hip_atomic_load(src + j, __ATOMIC_RELAXED, __HIP_MEMORY_SCOPE_AGENT);
                bool ok = true;
                #pragma unroll
                for (int j = 0; j < 8; ++j) ok &= ((u32)(hv[j] >> 32) == tag);
                if (ok) break;
                __builtin_amdgcn_s_sleep(1);
            }
            // payload -> LDS: 8 pairs = elems [ch*16, ch*16+16)
            #pragma unroll
            for (int j = 0; j < 4; ++j) {
                u64 pk = (u64)(u32)hv[2*j] | ((u64)(u32)hv[2*j + 1] << 32);
                int e = ch*16 + 4*j;
                int phys = ((e & ~7) ^ swzp) | (e & 7);
                *(u64*)&h_lds[sbp][phys] = pk;
            }
        }
        __syncthreads();   // B1: h_lds + x stash visible

        // ---- recurrent MFMAs ----
        #pragma unroll
        for (int kt = 0; kt < 16; ++kt) {
            bf16x8 a = *(const bf16x8*)&h_lds[cl][(kt*32 + kgrp*8) ^ ((cl & 7) << 3)];
            acc0 = __builtin_amdgcn_mfma_f32_16x16x32_bf16(a, whf[kt][0], acc0, 0, 0, 0);
            acc1 = __builtin_amdgcn_mfma_f32_16x16x32_bf16(a, whf[kt][1], acc1, 0, 0, 0);
        }

        // ---- preactivations to LDS: D row=(kgrp*4+r)=batch, col=cl ----
        #pragma unroll
        for (int r = 0; r < 4; ++r) {
            P_lds[kgrp*4 + r][wv*32 + cl]      = acc0[r];
            P_lds[kgrp*4 + r][wv*32 + 16 + cl] = acc1[r];
        }
        __syncthreads();   // B2: P visible

        // ---- activations: thread owns batch b, local units 2*u2, 2*u2+1 ----
        {
            int b = tid >> 5, u2 = tid & 31;
            float4 g0 = *(const float4*)&P_lds[b][u2*8];       // unit 2*u2
            float4 g1 = *(const float4*)&P_lds[b][u2*8 + 4];   // unit 2*u2+1
            float r0 = sigf(g0.x), f0 = sigf(g0.y), z0 = tanhfast(g0.z), o0 = sigf(g0.w);
            float r1 = sigf(g1.x), f1 = sigf(g1.y), z1 = tanhfast(g1.z), o1 = sigf(g1.w);
            c0 = f0*c0 + r0*z0;
            c1 = f1*c1 + r1*z1;
            float h0 = o0*tanhfast(c0);
            float h1 = o1*tanhfast(c1);
            if (t == TB - 1) {
                float2 hw = { h0, h1 };
                *(float2*)&out[64 + (size_t)(bg*GB + b)*HH + ug*NUNIT + 2*u2] = hw;
            }
            // publish tagged pair: u64 = (t+1)<<32 | bf16(h1)<<16 | bf16(h0)
            u64 v = (((u64)(u32)(t + 1)) << 32)
                  | (u64)((bfbits(h0) & 0xFFFFu) | (bfbits(h1) << 16));
            size_t idx = ((size_t)(t & 1))*NB*NPAIR
                       + (size_t)(bg*GB + b)*NPAIR + ug*NPB + u2;
            __hip_atomic_store(tagH + idx, v, __ATOMIC_RELAXED, __HIP_MEMORY_SCOPE_AGENT);
        }
        // no end-of-step barrier, no flag, no fence
    }

    // ---- final FC head: block ug==0 of each group ----
    if (ug == 0) {
        const u64* src = tagH + ((size_t)((TB - 1) & 1))*NB*NPAIR
                              + (size_t)(bg*GB + sbp)*NPAIR + ch*8;
        u64 hv[8];
        for (;;) {
            #pragma unroll
            for (int j = 0; j < 8; ++j)
                hv[j] = __hip_atomic_load(src + j, __ATOMIC_RELAXED, __HIP_MEMORY_SCOPE_AGENT);
            bool ok = true;
            #pragma unroll
            for (int j = 0; j < 8; ++j) ok &= ((u32)(hv[j] >> 32) == (u32)TB);
            if (ok) break;
            __builtin_amdgcn_s_sleep(1);
        }
        float s = 0.f;
        #pragma unroll
        for (int j = 0; j < 8; ++j) {
            u32 pl = (u32)hv[j];
            int p  = ch*8 + j;
            float h0 = __uint_as_float((pl & 0xFFFFu) << 16);
            float h1 = __uint_as_float(pl & 0xFFFF0000u);
            s += h0 * Wfc[2*p] + h1 * Wfc[2*p + 1];
        }
        __syncthreads();           // all act-phase P_lds reads done; safe to reuse
        P_lds[sbp][ch] = s;
        __syncthreads();
        if (tid < 16) {
            float acc = 0.f;
            #pragma unroll
            for (int q = 0; q < 32; ++q) acc += P_lds[tid][q];
            out[bg*GB + tid] = sigf(acc + bfc[0]);
        }
    }
}

extern "C" void kernel_launch(void* const* d_in, const int* in_sizes, int n_in,
                              void* d_out, int out_size, void* d_ws, size_t ws_size,
                              hipStream_t stream) {
    (void)in_sizes; (void)n_in; (void)out_size; (void)ws_size;
    const int*   words = (const int*)d_in[0];
    const float* emb   = (const float*)d_in[1];
    const float* Wi    = (const float*)d_in[2];
    const float* bi    = (const float*)d_in[3];
    const float* Wh    = (const float*)d_in[4];
    const float* bh    = (const float*)d_in[5];
    const float* Wfc   = (const float*)d_in[6];
    const float* bfc   = (const float*)d_in[7];
    float* out = (float*)d_out;

    u64* tagH = (u64*)d_ws;

    // zero tags every launch (tag 0 matches no step; h_{-1} handled by LDS zero)
    hipMemsetAsync(d_ws, 0, (size_t)2*NB*NPAIR*sizeof(u64), stream);

    lstm_persistent<<<dim3(NG*NBLK), dim3(NT), 0, stream>>>(
        words, emb, Wi, bi, Wh, bh, Wfc, bfc, out, tagH);
}